// Round 7
// baseline (435.240 us; speedup 1.0000x reference)
//
#include <hip/hip_runtime.h>
#include <hip/hip_bf16.h>
#include <type_traits>

typedef __hip_bfloat16 bf16;
typedef short bf16x8 __attribute__((ext_vector_type(8)));
typedef float f32x4 __attribute__((ext_vector_type(4)));

#define NB 8      // batch
#define SM 512    // block size M
#define SL 1024   // attn span L
#define SH 512    // hidden
#define NH 8      // heads
#define HD 64     // head dim
#define SN 1536   // M + L (key length)

static __device__ __forceinline__ short bf_bits(float x) {
  union { bf16 b; short s; } u; u.b = __float2bfloat16(x); return u.s;
}
static __device__ __forceinline__ bf16x8 ld8any(const bf16* p) {
  return *reinterpret_cast<const bf16x8*>(p);
}
static __device__ __forceinline__ bf16x8 ld8any(const float* p) {
  float4 a = *reinterpret_cast<const float4*>(p);
  float4 b = *reinterpret_cast<const float4*>(p + 4);
  bf16x8 r;
  r[0] = bf_bits(a.x); r[1] = bf_bits(a.y); r[2] = bf_bits(a.z); r[3] = bf_bits(a.w);
  r[4] = bf_bits(b.x); r[5] = bf_bits(b.y); r[6] = bf_bits(b.z); r[7] = bf_bits(b.w);
  return r;
}
static __device__ __forceinline__ f32x4 mfma16(bf16x8 a, bf16x8 b, f32x4 c) {
  return __builtin_amdgcn_mfma_f32_16x16x32_bf16(a, b, c, 0, 0, 0);
}

// ---------------------------------------------------------------------------
// Y[R x 512] = X[R x 512] @ W^T, 128x128 tile, XCD-swizzled 1-D grid.
// MODE 0: row-major.  MODE 1: k_head [((b*8+h)*1536+s)*64+d].
// MODE 2: vT [((b*8+h)*64+d)*1536+s] (staged transposed).
// ---------------------------------------------------------------------------
#define TSTR 136

template <int MODE, typename TX, typename TW, typename TY>
__global__ __launch_bounds__(256) void gemm128(const TX* __restrict__ X,
                                               const TW* __restrict__ W,
                                               TY* __restrict__ Y) {
  constexpr bool DIRECT = (MODE == 0 && std::is_same<TY, float>::value);
  __shared__ __align__(16) bf16 tile[DIRECT ? 8 : 128 * TSTR];
  const int id   = blockIdx.x;
  const int s_   = id >> 3;
  const int xblk = (id & 7) + 8 * (s_ >> 2);
  const int yblk = s_ & 3;
  const int tid  = threadIdx.x;
  const int lane = tid & 63, wave = tid >> 6;
  const int col16 = lane & 15, quad = lane >> 4, kq = quad << 3;
  const int m0 = xblk * 128 + (wave >> 1) * 64;
  const int n0 = yblk * 128 + (wave & 1) * 64;
  const TX* xr = X + (size_t)(m0 + col16) * SH + kq;
  const TW* wr = W + (size_t)(n0 + col16) * SH + kq;
  f32x4 acc[4][4];
#pragma unroll
  for (int i = 0; i < 4; ++i)
#pragma unroll
    for (int j = 0; j < 4; ++j) acc[i][j] = f32x4{0.f,0.f,0.f,0.f};
#pragma unroll
  for (int k0 = 0; k0 < SH; k0 += 32) {
    bf16x8 af[4], bfr[4];
#pragma unroll
    for (int t = 0; t < 4; ++t) af[t]  = ld8any(xr + (size_t)(t*16) * SH + k0);
#pragma unroll
    for (int t = 0; t < 4; ++t) bfr[t] = ld8any(wr + (size_t)(t*16) * SH + k0);
#pragma unroll
    for (int mt = 0; mt < 4; ++mt)
#pragma unroll
      for (int nt = 0; nt < 4; ++nt)
        acc[mt][nt] = mfma16(af[mt], bfr[nt], acc[mt][nt]);
  }

  if constexpr (DIRECT) {
#pragma unroll
    for (int mt = 0; mt < 4; ++mt)
#pragma unroll
      for (int r = 0; r < 4; ++r) {
        const int row = m0 + mt*16 + quad*4 + r;
        float* yr = (float*)Y + (size_t)row * SH + n0 + col16;
#pragma unroll
        for (int nt = 0; nt < 4; ++nt) yr[nt*16] = acc[mt][nt][r];
      }
  } else {
#pragma unroll
    for (int mt = 0; mt < 4; ++mt)
#pragma unroll
      for (int r = 0; r < 4; ++r) {
        const int row_loc = (wave >> 1)*64 + mt*16 + quad*4 + r;
#pragma unroll
        for (int nt = 0; nt < 4; ++nt) {
          const int col_loc = (wave & 1)*64 + nt*16 + col16;
          if constexpr (MODE == 2)
            tile[col_loc * TSTR + row_loc] = __float2bfloat16(acc[mt][nt][r]);
          else
            tile[row_loc * TSTR + col_loc] = __float2bfloat16(acc[mt][nt][r]);
        }
      }
    __syncthreads();
    const int a  = tid >> 1;
    const int hh = tid & 1;
    const bf16* src = tile + a * TSTR + hh * 64;
    bf16* dst;
    if constexpr (MODE == 0) {
      const int row = xblk*128 + a;
      dst = (bf16*)Y + (size_t)row * SH + yblk*128 + hh*64;
    } else if constexpr (MODE == 1) {
      const int row = xblk*128 + a;
      const int b = row / SN, sr = row - b * SN;
      const int col0 = yblk*128 + hh*64;
      const int h = col0 >> 6;
      dst = (bf16*)Y + (size_t)((b*NH + h)*SN + sr) * HD;
    } else {
      const int col = yblk*128 + a;
      const int h = col >> 6, d = col & 63;
      const int row0 = xblk*128 + hh*64;
      const int b = row0 / SN, sr0 = row0 - b * SN;
      dst = (bf16*)Y + (size_t)((b*NH + h)*HD + d) * SN + sr0;
    }
#pragma unroll
    for (int i = 0; i < 8; ++i)
      reinterpret_cast<uint4*>(dst)[i] = reinterpret_cast<const uint4*>(src)[i];
  }
}

// ---------------------------------------------------------------------------
// peT[l][d] = bf16(pe[d][l])
// ---------------------------------------------------------------------------
__global__ void transpose_pe(const float* __restrict__ pe, bf16* __restrict__ peT) {
  int idx = blockIdx.x * 256 + threadIdx.x;
  int l = idx >> 6, d = idx & 63;
  peT[idx] = __float2bfloat16(pe[d * SL + l]);
}

// ---------------------------------------------------------------------------
// Split attention: one WAVE per (head, m-tile16, half-span). No __syncthreads.
// Each wave: 8 chunks of 64 rel cols, online softmax, partial O/M/S out.
// grid = 1024 blocks x 256 (4 waves). blockIdx = h + 8*g; unit g2 = g*4+w:
// half = g2&1, mt = (g2>>1)&31, b = g2>>6.  XCD: all head-h blocks on XCD h.
// ---------------------------------------------------------------------------
#define CSTRW 81   // cont f32 row stride (80 + 1)
#define PSTRW 65   // pos  f32 row stride (64 + 1)
#define BSTRW 104  // P bf16 row stride (96 + 8, 16B rows)

__global__ __launch_bounds__(256) void attn_split(
    const bf16* __restrict__ qp, const bf16* __restrict__ Kh,
    const bf16* __restrict__ VT, const bf16* __restrict__ peT,
    const float* __restrict__ spanv,
    float* __restrict__ part_o, float* __restrict__ part_ms) {
  __shared__ __align__(16) float cont_s[4][16][CSTRW];
  __shared__ __align__(16) float pos_s[4][16][PSTRW];
  __shared__ __align__(16) bf16  P_s[4][16][BSTRW];

  const int tid  = threadIdx.x;
  const int lane = tid & 63;
  const int w    = tid >> 6;
  const int h  = blockIdx.x & 7;
  const int g2 = (blockIdx.x >> 3) * 4 + w;
  const int half = g2 & 1;
  const int mt   = (g2 >> 1) & 31;
  const int b    = g2 >> 6;
  const int hb = b * 8 + h;
  const int m0 = mt * 16;
  const int col16 = lane & 15, quad = lane >> 4, kq = quad << 3;

  // zero this wave's P band (cells outside band stay 0 across all chunks)
  {
    bf16* pz = &P_s[w][0][0];
    for (int i = lane; i < 16 * BSTRW; i += 64) pz[i] = __float2bfloat16(0.0f);
  }

  // q fragments (rows m0..m0+15 of this head)
  const bf16* qb = qp + (size_t)(b*SM + m0 + col16) * SH + h*HD + kq;
  const bf16x8 qf0 = ld8any(qb);
  const bf16x8 qf1 = ld8any(qb + 32);

  const bf16* kb = Kh + (size_t)(hb * SN) * HD + kq;
  const bf16* vb = VT + (size_t)(hb * HD) * SN;

  const int srow = lane >> 2, sj = lane & 3;   // softmax: 16 rows x 4 lanes
  float Mrun = -1.0e30f, Srun = 0.0f;
  const float span = spanv[h];
  f32x4 o[4] = {{0.f,0.f,0.f,0.f},{0.f,0.f,0.f,0.f},
                {0.f,0.f,0.f,0.f},{0.f,0.f,0.f,0.f}};

  for (int ch = half * 8; ch < half * 8 + 8; ++ch) {
    const int l0 = ch << 6;
    const int nb_ = m0 + l0;          // abs key base; max 496+960, +79 < 1536

    // ---- phase 1: cont (5 tiles, span 80) + pos (4 tiles, 64) -> LDS ----
    f32x4 ca[5], pa[4];
#pragma unroll
    for (int t = 0; t < 5; ++t) {
      const bf16* kr = kb + (size_t)(nb_ + t*16 + col16) * HD;
      f32x4 c = {0.f,0.f,0.f,0.f};
      c = mfma16(qf0, ld8any(kr),      c);
      c = mfma16(qf1, ld8any(kr + 32), c);
      ca[t] = c;
    }
#pragma unroll
    for (int t = 0; t < 4; ++t) {
      const bf16* pr = peT + (size_t)(l0 + t*16 + col16) * HD + kq;
      f32x4 c = {0.f,0.f,0.f,0.f};
      c = mfma16(qf0, ld8any(pr),      c);
      c = mfma16(qf1, ld8any(pr + 32), c);
      pa[t] = c;
    }
#pragma unroll
    for (int r = 0; r < 4; ++r) {
      const int row = quad*4 + r;
#pragma unroll
      for (int t = 0; t < 5; ++t) cont_s[w][row][t*16 + col16] = ca[t][r];
#pragma unroll
      for (int t = 0; t < 4; ++t) pos_s[w][row][t*16 + col16]  = pa[t][r];
    }
    // same-wave LDS RAW: compiler inserts lgkmcnt; no barrier needed.

    // ---- phase 2: combine + online softmax (16 cols per lane) ----
    float sc[16];
    float mc = -1.0e30f;
    const float* crow = &cont_s[w][srow][srow + sj*16];
    const float* prow = &pos_s[w][srow][sj*16];
#pragma unroll
    for (int i = 0; i < 16; ++i) {
      float v = (crow[i] + prow[i]) * 0.125f;
      sc[i] = v;
      mc = fmaxf(mc, v);
    }
    mc = fmaxf(mc, __shfl_xor(mc, 1));
    mc = fmaxf(mc, __shfl_xor(mc, 2));
    const float Mnew = fmaxf(Mrun, mc);
    const float alpha = __expf(Mrun - Mnew);
    float ls = 0.0f;
    bf16* pwrow = &P_s[w][srow][srow + sj*16];
#pragma unroll
    for (int i = 0; i < 16; ++i) {
      float p = __expf(sc[i] - Mnew);
      ls += p;
      const float tpl = (float)(l0 + sj*16 + i) - 1023.0f;
      float mv = (tpl + span * 1024.0f) * 0.03125f + 1.0f;
      mv = fminf(fmaxf(mv, 0.0f), 1.0f);
      pwrow[i] = __float2bfloat16(p * mv);
    }
    ls += __shfl_xor(ls, 1);
    ls += __shfl_xor(ls, 2);
    Srun = Srun * alpha + ls;
    Mrun = Mnew;

    // ---- phase 3: rescale O by per-row alpha (shfl), PV over 96-key span ----
    float al[4];
#pragma unroll
    for (int r = 0; r < 4; ++r) al[r] = __shfl(alpha, 16*quad + 4*r);
#pragma unroll
    for (int dt = 0; dt < 4; ++dt)
#pragma unroll
      for (int r = 0; r < 4; ++r) o[dt][r] *= al[r];
#pragma unroll
    for (int ks = 0; ks < 3; ++ks) {
      const bf16x8 ap = ld8any(&P_s[w][col16][ks*32 + kq]);
#pragma unroll
      for (int dt = 0; dt < 4; ++dt) {
        const bf16* v0 = vb + (size_t)(dt*16 + col16) * SN + nb_ + ks*32 + kq;
        o[dt] = mfma16(ap, ld8any(v0), o[dt]);
      }
    }
  }

  // ---- store partials ----
  const int u = ((b*8 + h)*32 + mt)*2 + half;
  float* po = part_o + (size_t)u * 1024;
#pragma unroll
  for (int dt = 0; dt < 4; ++dt)
#pragma unroll
    for (int r = 0; r < 4; ++r)
      po[(quad*4 + r)*64 + dt*16 + col16] = o[dt][r];
  if ((lane & 3) == 0) {
    part_ms[u*32 + srow]      = Mrun;
    part_ms[u*32 + 16 + srow] = Srun;
  }
}

// ---------------------------------------------------------------------------
// Merge the two half-span partials -> ctx (bf16). grid = 2048 x 256.
// ---------------------------------------------------------------------------
__global__ __launch_bounds__(256) void merge_attn(
    const float* __restrict__ part_o, const float* __restrict__ part_ms,
    bf16* __restrict__ ctx) {
  const int h  = blockIdx.x & 7;
  const int mt = (blockIdx.x >> 3) & 31;
  const int b  = blockIdx.x >> 8;
  const int base = (((b*8 + h)*32 + mt)) * 2;
  const int tid = threadIdx.x;
  const int d = tid & 63;
  const int rq = tid >> 6;
  const float* ms0 = part_ms + (size_t)base * 32;
  const float* ms1 = ms0 + 32;
  const float* o0 = part_o + (size_t)base * 1024;
  const float* o1 = o0 + 1024;
#pragma unroll
  for (int it = 0; it < 4; ++it) {
    const int row = it*4 + rq;
    const float M1 = ms0[row], S1 = ms0[16 + row];
    const float M2 = ms1[row], S2 = ms1[16 + row];
    const float M = fmaxf(M1, M2);
    const float w1 = __expf(M1 - M), w2 = __expf(M2 - M);
    const float val = (w1*o0[row*64 + d] + w2*o1[row*64 + d]) /
                      (w1*S1 + w2*S2);
    ctx[(size_t)(b*SM + mt*16 + row) * SH + h*HD + d] = __float2bfloat16(val);
  }
}

// ---------------------------------------------------------------------------
// Fallback fused attention (round-6 proven path): 16 rows/block, 2 waves.
// ---------------------------------------------------------------------------
#define MT 16
#define CSTR 84
#define PSTR 65
#define BSTR 104
#define QSTR 72

template <int FUSEDQ>
__global__ __launch_bounds__(128) void attn_kernel(
    const float* __restrict__ query, const float* __restrict__ Wq,
    const bf16* __restrict__ qp,
    const bf16* __restrict__ Kh, const bf16* __restrict__ VT,
    const bf16* __restrict__ peT, const float* __restrict__ spanv,
    bf16* __restrict__ ctx) {
  __shared__ __align__(16) float cont_lds[MT][CSTR];
  __shared__ __align__(16) float pos_lds[MT][PSTR];
  __shared__ __align__(16) bf16  P_lds[MT][BSTR];
  __shared__ __align__(16) bf16  q_lds[FUSEDQ ? MT*QSTR : 8];
  __shared__ float alpha_lds[MT];
  __shared__ float S_lds[MT];

  const int id = blockIdx.x;
  const int h  = id & 7;
  const int s_ = id >> 3;
  const int m0 = (s_ & 31) * MT;
  const int b  = s_ >> 5;
  const int hb = b * 8 + h;
  const int tid  = threadIdx.x;
  const int lane = tid & 63;
  const int w    = tid >> 6;
  const int col16 = lane & 15, quad = lane >> 4, kq = quad << 3;
  const int wr = quad << 2;

  for (int i = tid; i < MT * BSTR; i += 128)
    (&P_lds[0][0])[i] = __float2bfloat16(0.0f);

  bf16x8 qf0, qf1;
  if constexpr (FUSEDQ) {
    f32x4 qa0 = {0.f,0.f,0.f,0.f}, qa1 = qa0;
    const float* xq = query + (size_t)(b*SM + m0 + col16) * SH + kq;
    const float* w0 = Wq + (size_t)(h*HD + w*32 + col16) * SH + kq;
    const float* w1 = w0 + (size_t)16 * SH;
#pragma unroll
    for (int k0 = 0; k0 < SH; k0 += 32) {
      bf16x8 xa = ld8any(xq + k0);
      qa0 = mfma16(xa, ld8any(w0 + k0), qa0);
      qa1 = mfma16(xa, ld8any(w1 + k0), qa1);
    }
#pragma unroll
    for (int r = 0; r < 4; ++r) {
      q_lds[(wr + r)*QSTR + w*32 + col16]      = __float2bfloat16(qa0[r]);
      q_lds[(wr + r)*QSTR + w*32 + 16 + col16] = __float2bfloat16(qa1[r]);
    }
    __syncthreads();
    qf0 = ld8any(&q_lds[col16*QSTR + kq]);
    qf1 = ld8any(&q_lds[col16*QSTR + kq + 32]);
  } else {
    const bf16* qb = qp + (size_t)(b*SM + m0 + col16) * SH + h*HD + kq;
    qf0 = ld8any(qb);
    qf1 = ld8any(qb + 32);
  }

  const bf16* kb = Kh + (size_t)(hb * SN) * HD + kq;
  const bf16* vb = VT + (size_t)(hb * HD) * SN;

  const int srow = tid >> 3, sj = tid & 7;
  float Mrun = -1.0e30f, Srun = 0.0f;
  const float span = spanv[h];
  const int dt0 = w * 16, dt1 = (w + 2) * 16;
  f32x4 o0 = {0.f,0.f,0.f,0.f}, o1 = o0;

  for (int ch = 0; ch < 16; ++ch) {
    const int l0 = ch << 6;
    const int nb_ = m0 + l0;

    f32x4 ca0 = {0.f,0.f,0.f,0.f}, ca1 = ca0, ca2 = ca0, pa0 = ca0, pa1 = ca0;
    {
      const bf16* kr0 = kb + (size_t)(nb_ + w*16 + col16) * HD;
      ca0 = mfma16(qf0, ld8any(kr0),           ca0);
      ca0 = mfma16(qf1, ld8any(kr0 + 32),      ca0);
      const bf16* kr1 = kr0 + 32 * HD;
      ca1 = mfma16(qf0, ld8any(kr1),           ca1);
      ca1 = mfma16(qf1, ld8any(kr1 + 32),      ca1);
      if (w == 0) {
        const bf16* kr2 = kr0 + 64 * HD;
        ca2 = mfma16(qf0, ld8any(kr2),         ca2);
        ca2 = mfma16(qf1, ld8any(kr2 + 32),    ca2);
      }
      const bf16* pr0 = peT + (size_t)(l0 + w*16 + col16) * HD + kq;
      pa0 = mfma16(qf0, ld8any(pr0),           pa0);
      pa0 = mfma16(qf1, ld8any(pr0 + 32),      pa0);
      const bf16* pr1 = pr0 + 32 * HD;
      pa1 = mfma16(qf0, ld8any(pr1),           pa1);
      pa1 = mfma16(qf1, ld8any(pr1 + 32),      pa1);
    }
#pragma unroll
    for (int r = 0; r < 4; ++r) {
      cont_lds[wr + r][w*16 + col16]      = ca0[r];
      cont_lds[wr + r][w*16 + 32 + col16] = ca1[r];
      if (w == 0) cont_lds[wr + r][64 + col16] = ca2[r];
      pos_lds[wr + r][w*16 + col16]       = pa0[r];
      pos_lds[wr + r][w*16 + 32 + col16]  = pa1[r];
    }
    __syncthreads();

    float sc[8];
    float mc = -1.0e30f;
    const float* crow = &cont_lds[srow][srow + sj*8];
    const float* prow = &pos_lds[srow][sj*8];
#pragma unroll
    for (int i = 0; i < 8; ++i) {
      float v = (crow[i] + prow[i]) * 0.125f;
      sc[i] = v;
      mc = fmaxf(mc, v);
    }
    mc = fmaxf(mc, __shfl_xor(mc, 1));
    mc = fmaxf(mc, __shfl_xor(mc, 2));
    mc = fmaxf(mc, __shfl_xor(mc, 4));
    const float Mnew = fmaxf(Mrun, mc);
    const float alpha = __expf(Mrun - Mnew);
    float ls = 0.0f;
    bf16* pwrow = &P_lds[srow][srow + sj*8];
#pragma unroll
    for (int i = 0; i < 8; ++i) {
      float p = __expf(sc[i] - Mnew);
      ls += p;
      const float tpl = (float)(l0 + sj*8 + i) - 1023.0f;
      float mv = (tpl + span * 1024.0f) * 0.03125f + 1.0f;
      mv = fminf(fmaxf(mv, 0.0f), 1.0f);
      pwrow[i] = __float2bfloat16(p * mv);
    }
    ls += __shfl_xor(ls, 1);
    ls += __shfl_xor(ls, 2);
    ls += __shfl_xor(ls, 4);
    Srun = Srun * alpha + ls;
    Mrun = Mnew;
    if (sj == 0) { alpha_lds[srow] = alpha; S_lds[srow] = Srun; }
    __syncthreads();

    float al[4];
#pragma unroll
    for (int r = 0; r < 4; ++r) al[r] = alpha_lds[wr + r];
#pragma unroll
    for (int r = 0; r < 4; ++r) { o0[r] *= al[r]; o1[r] *= al[r]; }
#pragma unroll
    for (int ks = 0; ks < 3; ++ks) {
      const bf16x8 ap = ld8any(&P_lds[col16][ks*32 + kq]);
      const bf16* v0 = vb + (size_t)(dt0 + col16) * SN + nb_ + ks*32 + kq;
      const bf16* v1 = vb + (size_t)(dt1 + col16) * SN + nb_ + ks*32 + kq;
      o0 = mfma16(ap, ld8any(v0), o0);
      o1 = mfma16(ap, ld8any(v1), o1);
    }
  }

  bf16* cr = ctx + (size_t)(b*SM + m0 + wr) * SH + h*HD + col16;
#pragma unroll
  for (int r = 0; r < 4; ++r) {
    const float inv = 1.0f / S_lds[wr + r];
    cr[(size_t)r * SH + dt0] = __float2bfloat16(o0[r] * inv);
    cr[(size_t)r * SH + dt1] = __float2bfloat16(o1[r] * inv);
  }
}

// ---------------------------------------------------------------------------
extern "C" void kernel_launch(void* const* d_in, const int* in_sizes, int n_in,
                              void* d_out, int out_size, void* d_ws, size_t ws_size,
                              hipStream_t stream) {
  const float* query  = (const float*)d_in[0];
  const float* key    = (const float*)d_in[1];
  const float* value  = (const float*)d_in[2];
  const float* key_pe = (const float*)d_in[3];
  const float* Wq     = (const float*)d_in[4];
  const float* Wk     = (const float*)d_in[5];
  const float* Wv     = (const float*)d_in[6];
  const float* Wo     = (const float*)d_in[7];
  const float* spanv  = (const float*)d_in[8];
  float* out = (float*)d_out;

  bf16* ws = (bf16*)d_ws;
  if (ws_size >= (size_t)50987008) {
    // Path S: split attention + merge. 7 dispatches, 51.0 MB ws.
    bf16* k_head = ws;                    // 6291456 el
    bf16* vT     = k_head + 6291456;      // 6291456 el
    bf16* qp     = vT     + 6291456;      // 2097152 el
    bf16* ctx    = qp     + 2097152;      // 2097152 el
    bf16* peT    = ctx    + 2097152;      // 65536 el
    float* part_o  = (float*)(peT + 65536);       // 4096*1024 f32
    float* part_ms = part_o + 4096*1024;          // 4096*32 f32
    gemm128<1, float, float, bf16><<<384, 256, 0, stream>>>(key,   Wk, k_head);
    gemm128<2, float, float, bf16><<<384, 256, 0, stream>>>(value, Wv, vT);
    gemm128<0, float, float, bf16><<<128, 256, 0, stream>>>(query, Wq, qp);
    transpose_pe<<<256, 256, 0, stream>>>(key_pe, peT);
    attn_split<<<1024, 256, 0, stream>>>(qp, k_head, vT, peT, spanv,
                                         part_o, part_ms);
    merge_attn<<<2048, 256, 0, stream>>>(part_o, part_ms, ctx);
    gemm128<0, bf16, float, float><<<128, 256, 0, stream>>>(ctx, Wo, out);
  } else if (ws_size >= (size_t)33685504) {
    // Path A: precomputed q_proj + fused attention (round-6 proven).
    bf16* k_head = ws;
    bf16* vT     = k_head + 6291456;
    bf16* ctx    = vT     + 6291456;
    bf16* qp     = ctx    + 2097152;
    bf16* peT    = qp     + 2097152;
    gemm128<1, float, float, bf16><<<384, 256, 0, stream>>>(key,   Wk, k_head);
    gemm128<2, float, float, bf16><<<384, 256, 0, stream>>>(value, Wv, vT);
    gemm128<0, float, float, bf16><<<128, 256, 0, stream>>>(query, Wq, qp);
    transpose_pe<<<256, 256, 0, stream>>>(key_pe, peT);
    attn_kernel<0><<<2048, 128, 0, stream>>>(nullptr, nullptr, qp, k_head, vT,
                                             peT, spanv, ctx);
    gemm128<0, bf16, float, float><<<128, 256, 0, stream>>>(ctx, Wo, out);
  } else {
    // Path B: fused-q attention, 29.5 MB ws.
    bf16* k_head = ws;
    bf16* vT     = k_head + 6291456;
    bf16* ctx    = vT     + 6291456;
    bf16* peT    = ctx    + 2097152;
    gemm128<1, float, float, bf16><<<384, 256, 0, stream>>>(key,   Wk, k_head);
    gemm128<2, float, float, bf16><<<384, 256, 0, stream>>>(value, Wv, vT);
    transpose_pe<<<256, 256, 0, stream>>>(key_pe, peT);
    attn_kernel<1><<<2048, 128, 0, stream>>>(query, Wq, nullptr, k_head, vT,
                                             peT, spanv, ctx);
    gemm128<0, bf16, float, float><<<128, 256, 0, stream>>>(ctx, Wo, out);
  }
}

// Round 8
// 353.728 us; speedup vs baseline: 1.2304x; 1.2304x over previous
//
#include <hip/hip_runtime.h>
#include <hip/hip_bf16.h>
#include <type_traits>

typedef __hip_bfloat16 bf16;
typedef short bf16x8 __attribute__((ext_vector_type(8)));
typedef float f32x4 __attribute__((ext_vector_type(4)));

#define NB 8      // batch
#define SM 512    // block size M
#define SL 1024   // attn span L
#define SH 512    // hidden
#define NH 8      // heads
#define HD 64     // head dim
#define SN 1536   // M + L (key length)

static __device__ __forceinline__ short bf_bits(float x) {
  union { bf16 b; short s; } u; u.b = __float2bfloat16(x); return u.s;
}
static __device__ __forceinline__ bf16x8 ld8any(const bf16* p) {
  return *reinterpret_cast<const bf16x8*>(p);
}
static __device__ __forceinline__ bf16x8 ld8any(const float* p) {
  float4 a = *reinterpret_cast<const float4*>(p);
  float4 b = *reinterpret_cast<const float4*>(p + 4);
  bf16x8 r;
  r[0] = bf_bits(a.x); r[1] = bf_bits(a.y); r[2] = bf_bits(a.z); r[3] = bf_bits(a.w);
  r[4] = bf_bits(b.x); r[5] = bf_bits(b.y); r[6] = bf_bits(b.z); r[7] = bf_bits(b.w);
  return r;
}
static __device__ __forceinline__ f32x4 mfma16(bf16x8 a, bf16x8 b, f32x4 c) {
  return __builtin_amdgcn_mfma_f32_16x16x32_bf16(a, b, c, 0, 0, 0);
}

// ---------------------------------------------------------------------------
// f32 -> bf16 bulk conversion, 8 el/thread, fully coalesced.
// ---------------------------------------------------------------------------
__global__ __launch_bounds__(256) void conv_bf16(const float* __restrict__ src,
                                                 bf16* __restrict__ dst) {
  const int i = blockIdx.x * 256 + threadIdx.x;
  *reinterpret_cast<bf16x8*>(dst + (size_t)i * 8) = ld8any(src + (size_t)i * 8);
}

// 4 weight matrices in one dispatch: grid (128, 4).
__global__ __launch_bounds__(256) void conv_w4(const float* __restrict__ w0,
                                               const float* __restrict__ w1,
                                               const float* __restrict__ w2,
                                               const float* __restrict__ w3,
                                               bf16* __restrict__ dst) {
  const float* srcs[4] = {w0, w1, w2, w3};
  const float* s = srcs[blockIdx.y];
  bf16* d = dst + (size_t)blockIdx.y * 262144;
  const int i = blockIdx.x * 256 + threadIdx.x;
  *reinterpret_cast<bf16x8*>(d + (size_t)i * 8) = ld8any(s + (size_t)i * 8);
}

// ---------------------------------------------------------------------------
// Y[R x 512] = X[R x 512] @ W^T, 128x128 tile, XCD-swizzled 1-D grid.
// MODE 0: row-major.  MODE 1: k_head [((b*8+h)*1536+s)*64+d].
// MODE 2: vT [((b*8+h)*64+d)*1536+s] (staged transposed).
// ---------------------------------------------------------------------------
#define TSTR 136

template <int MODE, typename TX, typename TW, typename TY>
__global__ __launch_bounds__(256) void gemm128(const TX* __restrict__ X,
                                               const TW* __restrict__ W,
                                               TY* __restrict__ Y) {
  constexpr bool DIRECT = (MODE == 0 && std::is_same<TY, float>::value);
  __shared__ __align__(16) bf16 tile[DIRECT ? 8 : 128 * TSTR];
  const int id   = blockIdx.x;
  const int s_   = id >> 3;
  const int xblk = (id & 7) + 8 * (s_ >> 2);
  const int yblk = s_ & 3;
  const int tid  = threadIdx.x;
  const int lane = tid & 63, wave = tid >> 6;
  const int col16 = lane & 15, quad = lane >> 4, kq = quad << 3;
  const int m0 = xblk * 128 + (wave >> 1) * 64;
  const int n0 = yblk * 128 + (wave & 1) * 64;
  const TX* xr = X + (size_t)(m0 + col16) * SH + kq;
  const TW* wr = W + (size_t)(n0 + col16) * SH + kq;
  f32x4 acc[4][4];
#pragma unroll
  for (int i = 0; i < 4; ++i)
#pragma unroll
    for (int j = 0; j < 4; ++j) acc[i][j] = f32x4{0.f,0.f,0.f,0.f};
#pragma unroll
  for (int k0 = 0; k0 < SH; k0 += 32) {
    bf16x8 af[4], bfr[4];
#pragma unroll
    for (int t = 0; t < 4; ++t) af[t]  = ld8any(xr + (size_t)(t*16) * SH + k0);
#pragma unroll
    for (int t = 0; t < 4; ++t) bfr[t] = ld8any(wr + (size_t)(t*16) * SH + k0);
#pragma unroll
    for (int mt = 0; mt < 4; ++mt)
#pragma unroll
      for (int nt = 0; nt < 4; ++nt)
        acc[mt][nt] = mfma16(af[mt], bfr[nt], acc[mt][nt]);
  }

  if constexpr (DIRECT) {
#pragma unroll
    for (int mt = 0; mt < 4; ++mt)
#pragma unroll
      for (int r = 0; r < 4; ++r) {
        const int row = m0 + mt*16 + quad*4 + r;
        float* yr = (float*)Y + (size_t)row * SH + n0 + col16;
#pragma unroll
        for (int nt = 0; nt < 4; ++nt) yr[nt*16] = acc[mt][nt][r];
      }
  } else {
#pragma unroll
    for (int mt = 0; mt < 4; ++mt)
#pragma unroll
      for (int r = 0; r < 4; ++r) {
        const int row_loc = (wave >> 1)*64 + mt*16 + quad*4 + r;
#pragma unroll
        for (int nt = 0; nt < 4; ++nt) {
          const int col_loc = (wave & 1)*64 + nt*16 + col16;
          if constexpr (MODE == 2)
            tile[col_loc * TSTR + row_loc] = __float2bfloat16(acc[mt][nt][r]);
          else
            tile[row_loc * TSTR + col_loc] = __float2bfloat16(acc[mt][nt][r]);
        }
      }
    __syncthreads();
    const int a  = tid >> 1;
    const int hh = tid & 1;
    const bf16* src = tile + a * TSTR + hh * 64;
    bf16* dst;
    if constexpr (MODE == 0) {
      const int row = xblk*128 + a;
      dst = (bf16*)Y + (size_t)row * SH + yblk*128 + hh*64;
    } else if constexpr (MODE == 1) {
      const int row = xblk*128 + a;
      const int b = row / SN, sr = row - b * SN;
      const int col0 = yblk*128 + hh*64;
      const int h = col0 >> 6;
      dst = (bf16*)Y + (size_t)((b*NH + h)*SN + sr) * HD;
    } else {
      const int col = yblk*128 + a;
      const int h = col >> 6, d = col & 63;
      const int row0 = xblk*128 + hh*64;
      const int b = row0 / SN, sr0 = row0 - b * SN;
      dst = (bf16*)Y + (size_t)((b*NH + h)*HD + d) * SN + sr0;
    }
#pragma unroll
    for (int i = 0; i < 8; ++i)
      reinterpret_cast<uint4*>(dst)[i] = reinterpret_cast<const uint4*>(src)[i];
  }
}

// ---------------------------------------------------------------------------
// peT[l][d] = bf16(pe[d][l])
// ---------------------------------------------------------------------------
__global__ void transpose_pe(const float* __restrict__ pe, bf16* __restrict__ peT) {
  int idx = blockIdx.x * 256 + threadIdx.x;
  int l = idx >> 6, d = idx & 63;
  peT[idx] = __float2bfloat16(pe[d * SL + l]);
}

// ---------------------------------------------------------------------------
// Fused sliding-window attention (round-6 proven): 16 rows/block, 2 waves.
// 1-D grid 2048; id = h + 8*(mtile + 32*b) -> all blocks of head h on XCD h.
// ---------------------------------------------------------------------------
#define MT 16
#define CSTR 84
#define PSTR 65
#define BSTR 104
#define QSTR 72

template <int FUSEDQ>
__global__ __launch_bounds__(128) void attn_kernel(
    const float* __restrict__ query, const float* __restrict__ Wq,
    const bf16* __restrict__ qp,
    const bf16* __restrict__ Kh, const bf16* __restrict__ VT,
    const bf16* __restrict__ peT, const float* __restrict__ spanv,
    bf16* __restrict__ ctx) {
  __shared__ __align__(16) float cont_lds[MT][CSTR];
  __shared__ __align__(16) float pos_lds[MT][PSTR];
  __shared__ __align__(16) bf16  P_lds[MT][BSTR];
  __shared__ __align__(16) bf16  q_lds[FUSEDQ ? MT*QSTR : 8];
  __shared__ float alpha_lds[MT];
  __shared__ float S_lds[MT];

  const int id = blockIdx.x;
  const int h  = id & 7;
  const int s_ = id >> 3;
  const int m0 = (s_ & 31) * MT;
  const int b  = s_ >> 5;
  const int hb = b * 8 + h;
  const int tid  = threadIdx.x;
  const int lane = tid & 63;
  const int w    = tid >> 6;
  const int col16 = lane & 15, quad = lane >> 4, kq = quad << 3;
  const int wr = quad << 2;

  for (int i = tid; i < MT * BSTR; i += 128)
    (&P_lds[0][0])[i] = __float2bfloat16(0.0f);

  bf16x8 qf0, qf1;
  if constexpr (FUSEDQ) {
    f32x4 qa0 = {0.f,0.f,0.f,0.f}, qa1 = qa0;
    const float* xq = query + (size_t)(b*SM + m0 + col16) * SH + kq;
    const float* w0 = Wq + (size_t)(h*HD + w*32 + col16) * SH + kq;
    const float* w1 = w0 + (size_t)16 * SH;
#pragma unroll
    for (int k0 = 0; k0 < SH; k0 += 32) {
      bf16x8 xa = ld8any(xq + k0);
      qa0 = mfma16(xa, ld8any(w0 + k0), qa0);
      qa1 = mfma16(xa, ld8any(w1 + k0), qa1);
    }
#pragma unroll
    for (int r = 0; r < 4; ++r) {
      q_lds[(wr + r)*QSTR + w*32 + col16]      = __float2bfloat16(qa0[r]);
      q_lds[(wr + r)*QSTR + w*32 + 16 + col16] = __float2bfloat16(qa1[r]);
    }
    __syncthreads();
    qf0 = ld8any(&q_lds[col16*QSTR + kq]);
    qf1 = ld8any(&q_lds[col16*QSTR + kq + 32]);
  } else {
    const bf16* qb = qp + (size_t)(b*SM + m0 + col16) * SH + h*HD + kq;
    qf0 = ld8any(qb);
    qf1 = ld8any(qb + 32);
  }

  const bf16* kb = Kh + (size_t)(hb * SN) * HD + kq;
  const bf16* vb = VT + (size_t)(hb * HD) * SN;

  const int srow = tid >> 3, sj = tid & 7;
  float Mrun = -1.0e30f, Srun = 0.0f;
  const float span = spanv[h];
  const int dt0 = w * 16, dt1 = (w + 2) * 16;
  f32x4 o0 = {0.f,0.f,0.f,0.f}, o1 = o0;

  for (int ch = 0; ch < 16; ++ch) {
    const int l0 = ch << 6;
    const int nb_ = m0 + l0;

    f32x4 ca0 = {0.f,0.f,0.f,0.f}, ca1 = ca0, ca2 = ca0, pa0 = ca0, pa1 = ca0;
    {
      const bf16* kr0 = kb + (size_t)(nb_ + w*16 + col16) * HD;
      ca0 = mfma16(qf0, ld8any(kr0),           ca0);
      ca0 = mfma16(qf1, ld8any(kr0 + 32),      ca0);
      const bf16* kr1 = kr0 + 32 * HD;
      ca1 = mfma16(qf0, ld8any(kr1),           ca1);
      ca1 = mfma16(qf1, ld8any(kr1 + 32),      ca1);
      if (w == 0) {
        const bf16* kr2 = kr0 + 64 * HD;
        ca2 = mfma16(qf0, ld8any(kr2),         ca2);
        ca2 = mfma16(qf1, ld8any(kr2 + 32),    ca2);
      }
      const bf16* pr0 = peT + (size_t)(l0 + w*16 + col16) * HD + kq;
      pa0 = mfma16(qf0, ld8any(pr0),           pa0);
      pa0 = mfma16(qf1, ld8any(pr0 + 32),      pa0);
      const bf16* pr1 = pr0 + 32 * HD;
      pa1 = mfma16(qf0, ld8any(pr1),           pa1);
      pa1 = mfma16(qf1, ld8any(pr1 + 32),      pa1);
    }
#pragma unroll
    for (int r = 0; r < 4; ++r) {
      cont_lds[wr + r][w*16 + col16]      = ca0[r];
      cont_lds[wr + r][w*16 + 32 + col16] = ca1[r];
      if (w == 0) cont_lds[wr + r][64 + col16] = ca2[r];
      pos_lds[wr + r][w*16 + col16]       = pa0[r];
      pos_lds[wr + r][w*16 + 32 + col16]  = pa1[r];
    }
    __syncthreads();

    float sc[8];
    float mc = -1.0e30f;
    const float* crow = &cont_lds[srow][srow + sj*8];
    const float* prow = &pos_lds[srow][sj*8];
#pragma unroll
    for (int i = 0; i < 8; ++i) {
      float v = (crow[i] + prow[i]) * 0.125f;
      sc[i] = v;
      mc = fmaxf(mc, v);
    }
    mc = fmaxf(mc, __shfl_xor(mc, 1));
    mc = fmaxf(mc, __shfl_xor(mc, 2));
    mc = fmaxf(mc, __shfl_xor(mc, 4));
    const float Mnew = fmaxf(Mrun, mc);
    const float alpha = __expf(Mrun - Mnew);
    float ls = 0.0f;
    bf16* pwrow = &P_lds[srow][srow + sj*8];
#pragma unroll
    for (int i = 0; i < 8; ++i) {
      float p = __expf(sc[i] - Mnew);
      ls += p;
      const float tpl = (float)(l0 + sj*8 + i) - 1023.0f;
      float mv = (tpl + span * 1024.0f) * 0.03125f + 1.0f;
      mv = fminf(fmaxf(mv, 0.0f), 1.0f);
      pwrow[i] = __float2bfloat16(p * mv);
    }
    ls += __shfl_xor(ls, 1);
    ls += __shfl_xor(ls, 2);
    ls += __shfl_xor(ls, 4);
    Srun = Srun * alpha + ls;
    Mrun = Mnew;
    if (sj == 0) { alpha_lds[srow] = alpha; S_lds[srow] = Srun; }
    __syncthreads();

    float al[4];
#pragma unroll
    for (int r = 0; r < 4; ++r) al[r] = alpha_lds[wr + r];
#pragma unroll
    for (int r = 0; r < 4; ++r) { o0[r] *= al[r]; o1[r] *= al[r]; }
#pragma unroll
    for (int ks = 0; ks < 3; ++ks) {
      const bf16x8 ap = ld8any(&P_lds[col16][ks*32 + kq]);
      const bf16* v0 = vb + (size_t)(dt0 + col16) * SN + nb_ + ks*32 + kq;
      const bf16* v1 = vb + (size_t)(dt1 + col16) * SN + nb_ + ks*32 + kq;
      o0 = mfma16(ap, ld8any(v0), o0);
      o1 = mfma16(ap, ld8any(v1), o1);
    }
  }

  bf16* cr = ctx + (size_t)(b*SM + m0 + wr) * SH + h*HD + col16;
#pragma unroll
  for (int r = 0; r < 4; ++r) {
    const float inv = 1.0f / S_lds[wr + r];
    cr[(size_t)r * SH + dt0] = __float2bfloat16(o0[r] * inv);
    cr[(size_t)r * SH + dt1] = __float2bfloat16(o1[r] * inv);
  }
}

// ---------------------------------------------------------------------------
extern "C" void kernel_launch(void* const* d_in, const int* in_sizes, int n_in,
                              void* d_out, int out_size, void* d_ws, size_t ws_size,
                              hipStream_t stream) {
  const float* query  = (const float*)d_in[0];
  const float* key    = (const float*)d_in[1];
  const float* value  = (const float*)d_in[2];
  const float* key_pe = (const float*)d_in[3];
  const float* Wq     = (const float*)d_in[4];
  const float* Wk     = (const float*)d_in[5];
  const float* Wv     = (const float*)d_in[6];
  const float* Wo     = (const float*)d_in[7];
  const float* spanv  = (const float*)d_in[8];
  float* out = (float*)d_out;

  bf16* ws = (bf16*)d_ws;
  if (ws_size >= (size_t)48365568) {
    // Path C: bf16-converted GEMM pipeline. 48.4 MB ws (ws>=51MB proven r7).
    bf16* stg    = ws;                    // 6291456 el, reused key->value
    bf16* k_head = stg    + 6291456;      // 6291456
    bf16* vT     = k_head + 6291456;      // 6291456
    bf16* qp     = vT     + 6291456;      // 2097152
    bf16* ctx    = qp     + 2097152;      // 2097152
    bf16* peT    = ctx    + 2097152;      // 65536
    bf16* Wb     = peT    + 65536;        // 4 x 262144 (q,k,v,o)
    bf16* Wq_b = Wb, *Wk_b = Wb + 262144, *Wv_b = Wb + 524288, *Wo_b = Wb + 786432;

    conv_w4<<<dim3(128, 4), 256, 0, stream>>>(Wq, Wk, Wv, Wo, Wb);
    transpose_pe<<<256, 256, 0, stream>>>(key_pe, peT);

    conv_bf16<<<3072, 256, 0, stream>>>(key, stg);
    gemm128<1, bf16, bf16, bf16><<<384, 256, 0, stream>>>(stg, Wk_b, k_head);
    conv_bf16<<<3072, 256, 0, stream>>>(value, stg);   // safe: prior GEMM done
    gemm128<2, bf16, bf16, bf16><<<384, 256, 0, stream>>>(stg, Wv_b, vT);
    gemm128<0, float, bf16, bf16><<<128, 256, 0, stream>>>(query, Wq_b, qp);

    attn_kernel<0><<<2048, 128, 0, stream>>>(nullptr, nullptr, qp, k_head, vT,
                                             peT, spanv, ctx);
    gemm128<0, bf16, bf16, float><<<128, 256, 0, stream>>>(ctx, Wo_b, out);
  } else {
    // Path B (fallback): fused-q attention, f32 GEMM reads, 29.5 MB ws.
    bf16* k_head = ws;
    bf16* vT     = k_head + 6291456;
    bf16* ctx    = vT     + 6291456;
    bf16* peT    = ctx    + 2097152;
    gemm128<1, float, float, bf16><<<384, 256, 0, stream>>>(key,   Wk, k_head);
    gemm128<2, float, float, bf16><<<384, 256, 0, stream>>>(value, Wv, vT);
    transpose_pe<<<256, 256, 0, stream>>>(key_pe, peT);
    attn_kernel<1><<<2048, 128, 0, stream>>>(query, Wq, nullptr, k_head, vT,
                                             peT, spanv, ctx);
    gemm128<0, bf16, float, float><<<128, 256, 0, stream>>>(ctx, Wo, out);
  }
}

// Round 9
// 348.199 us; speedup vs baseline: 1.2500x; 1.0159x over previous
//
#include <hip/hip_runtime.h>
#include <hip/hip_bf16.h>
#include <type_traits>

typedef __hip_bfloat16 bf16;
typedef short bf16x8 __attribute__((ext_vector_type(8)));
typedef float f32x4 __attribute__((ext_vector_type(4)));

#define NB 8      // batch
#define SM 512    // block size M
#define SL 1024   // attn span L
#define SH 512    // hidden
#define NH 8      // heads
#define HD 64     // head dim
#define SN 1536   // M + L (key length)

static __device__ __forceinline__ short bf_bits(float x) {
  union { bf16 b; short s; } u; u.b = __float2bfloat16(x); return u.s;
}
static __device__ __forceinline__ bf16x8 ld8any(const bf16* p) {
  return *reinterpret_cast<const bf16x8*>(p);
}
static __device__ __forceinline__ bf16x8 ld8any(const float* p) {
  float4 a = *reinterpret_cast<const float4*>(p);
  float4 b = *reinterpret_cast<const float4*>(p + 4);
  bf16x8 r;
  r[0] = bf_bits(a.x); r[1] = bf_bits(a.y); r[2] = bf_bits(a.z); r[3] = bf_bits(a.w);
  r[4] = bf_bits(b.x); r[5] = bf_bits(b.y); r[6] = bf_bits(b.z); r[7] = bf_bits(b.w);
  return r;
}
static __device__ __forceinline__ void st1(bf16* p, float v) { *p = __float2bfloat16(v); }
static __device__ __forceinline__ void st1(float* p, float v) { *p = v; }
static __device__ __forceinline__ f32x4 mfma16(bf16x8 a, bf16x8 b, f32x4 c) {
  return __builtin_amdgcn_mfma_f32_16x16x32_bf16(a, b, c, 0, 0, 0);
}

// ---------------------------------------------------------------------------
// f32 -> bf16 bulk conversion, 8 el/thread, fully coalesced.
// ---------------------------------------------------------------------------
__global__ __launch_bounds__(256) void conv_bf16(const float* __restrict__ src,
                                                 bf16* __restrict__ dst) {
  const int i = blockIdx.x * 256 + threadIdx.x;
  *reinterpret_cast<bf16x8*>(dst + (size_t)i * 8) = ld8any(src + (size_t)i * 8);
}

__global__ __launch_bounds__(256) void conv_w4(const float* __restrict__ w0,
                                               const float* __restrict__ w1,
                                               const float* __restrict__ w2,
                                               const float* __restrict__ w3,
                                               bf16* __restrict__ dst) {
  const float* srcs[4] = {w0, w1, w2, w3};
  const float* s = srcs[blockIdx.y];
  bf16* d = dst + (size_t)blockIdx.y * 262144;
  const int i = blockIdx.x * 256 + threadIdx.x;
  *reinterpret_cast<bf16x8*>(d + (size_t)i * 8) = ld8any(s + (size_t)i * 8);
}

// ---------------------------------------------------------------------------
// Y[R x 512] = X[R x 512] @ W^T. BM=128, BN=64 (64 = head dim -> MODE1/2
// head-aligned). 4 waves, wave tile 64x32. grid = (R/128)*8, XCD-swizzled:
// id = xcd + 8*(yblk + 8*xhi); xblk = xcd + 8*xhi.
// MODE 0: row-major.  MODE 1: k_head [((b*8+h)*1536+s)*64+d] (direct, h=yblk).
// MODE 2: vT [((b*8+h)*64+d)*1536+s] (LDS-staged transpose).
// ---------------------------------------------------------------------------
#define T2STR 136

template <int MODE, typename TX, typename TW, typename TY>
__global__ __launch_bounds__(256) void gemmbn64(const TX* __restrict__ X,
                                                const TW* __restrict__ W,
                                                TY* __restrict__ Y) {
  __shared__ __align__(16) bf16 tile[(MODE == 2) ? 64 * T2STR : 8];
  const int id   = blockIdx.x;
  const int s_   = id >> 3;
  const int xblk = (id & 7) + 8 * (s_ >> 3);
  const int yblk = s_ & 7;
  const int tid  = threadIdx.x;
  const int lane = tid & 63, w = tid >> 6;
  const int col16 = lane & 15, quad = lane >> 4, kq = quad << 3;
  const int wm = w >> 1, wn = w & 1;
  const int m0 = xblk * 128 + wm * 64;
  const int n0 = yblk * 64 + wn * 32;
  const TX* xr = X + (size_t)(m0 + col16) * SH + kq;
  const TW* wr = W + (size_t)(n0 + col16) * SH + kq;
  f32x4 acc[4][2];
#pragma unroll
  for (int i = 0; i < 4; ++i)
#pragma unroll
    for (int j = 0; j < 2; ++j) acc[i][j] = f32x4{0.f,0.f,0.f,0.f};
#pragma unroll
  for (int k0 = 0; k0 < SH; k0 += 32) {
    bf16x8 af[4], bfr[2];
#pragma unroll
    for (int t = 0; t < 4; ++t) af[t]  = ld8any(xr + (size_t)(t*16) * SH + k0);
#pragma unroll
    for (int t = 0; t < 2; ++t) bfr[t] = ld8any(wr + (size_t)(t*16) * SH + k0);
#pragma unroll
    for (int mt = 0; mt < 4; ++mt)
#pragma unroll
      for (int nt = 0; nt < 2; ++nt)
        acc[mt][nt] = mfma16(af[mt], bfr[nt], acc[mt][nt]);
  }

  if constexpr (MODE == 0) {
#pragma unroll
    for (int mt = 0; mt < 4; ++mt)
#pragma unroll
      for (int r = 0; r < 4; ++r) {
        const int row = m0 + mt*16 + quad*4 + r;
        TY* yr = Y + (size_t)row * SH + n0 + col16;
        st1(yr,      acc[mt][0][r]);
        st1(yr + 16, acc[mt][1][r]);
      }
  } else if constexpr (MODE == 1) {
#pragma unroll
    for (int mt = 0; mt < 4; ++mt)
#pragma unroll
      for (int r = 0; r < 4; ++r) {
        const int row = m0 + mt*16 + quad*4 + r;
        const int b = row / SN, sr = row - b * SN;
        bf16* yr = (bf16*)Y + (size_t)((b*NH + yblk)*SN + sr) * HD
                 + wn*32 + col16;
        yr[0]  = __float2bfloat16(acc[mt][0][r]);
        yr[16] = __float2bfloat16(acc[mt][1][r]);
      }
  } else {
    // stage transposed: tile[d][row_loc]
#pragma unroll
    for (int mt = 0; mt < 4; ++mt)
#pragma unroll
      for (int r = 0; r < 4; ++r) {
        const int row_loc = wm*64 + mt*16 + quad*4 + r;
#pragma unroll
        for (int nt = 0; nt < 2; ++nt) {
          const int d = wn*32 + nt*16 + col16;
          tile[d * T2STR + row_loc] = __float2bfloat16(acc[mt][nt][r]);
        }
      }
    __syncthreads();
    const int d  = tid >> 2;      // 0..63
    const int hq = tid & 3;       // 32-row quarter
    const bf16* src = tile + d * T2STR + hq * 32;
    const int row0 = xblk*128 + hq*32;
    const int b = row0 / SN, sr0 = row0 - b * SN;
    bf16* dst = (bf16*)Y + (size_t)((b*NH + yblk)*HD + d) * SN + sr0;
#pragma unroll
    for (int i = 0; i < 4; ++i)
      reinterpret_cast<uint4*>(dst)[i] = reinterpret_cast<const uint4*>(src)[i];
  }
}

// ---------------------------------------------------------------------------
// peT[l][d] = bf16(pe[d][l])
// ---------------------------------------------------------------------------
__global__ void transpose_pe(const float* __restrict__ pe, bf16* __restrict__ peT) {
  int idx = blockIdx.x * 256 + threadIdx.x;
  int l = idx >> 6, d = idx & 63;
  peT[idx] = __float2bfloat16(pe[d * SL + l]);
}

// ---------------------------------------------------------------------------
// 4-wave fused attention: 16 rows/unit, one unit per 256-thread block.
// grid 2048 -> 8 blocks/CU x 4 waves = 32 waves/CU. 2 barriers/chunk.
// Phase1 split: w0 cont{0,16}, w1 cont{32,48}, w2 cont{64}+pos{0},
// w3 pos{16,32,48}. Phase2: 16 lanes/row, 4 cols each. Phase3: d-tile=w*16.
// ---------------------------------------------------------------------------
#define CSTR4 84
#define PSTR4 65
#define BSTR4 104

__global__ __launch_bounds__(256) void attn4(
    const bf16* __restrict__ qp, const bf16* __restrict__ Kh,
    const bf16* __restrict__ VT, const bf16* __restrict__ peT,
    const float* __restrict__ spanv, bf16* __restrict__ ctx) {
  __shared__ __align__(16) float cont_s[16][CSTR4];
  __shared__ __align__(16) float pos_s[16][PSTR4];
  __shared__ __align__(16) bf16  P_s[16][BSTR4];
  __shared__ float alpha_s[16];
  __shared__ float S_s[16];

  const int id = blockIdx.x;
  const int h  = id & 7;
  const int s_ = id >> 3;
  const int m0 = (s_ & 31) * 16;
  const int b  = s_ >> 5;
  const int hb = b * 8 + h;
  const int tid = threadIdx.x, lane = tid & 63, w = tid >> 6;
  const int col16 = lane & 15, quad = lane >> 4, kq = quad << 3;
  const int wr = quad << 2;

  // zero P band once (band positions are chunk-invariant; init visible after
  // the first phase-1 barrier, before any P_s read in phase 3)
  for (int i = tid; i < 16 * BSTR4; i += 256)
    (&P_s[0][0])[i] = __float2bfloat16(0.0f);

  const bf16* qb = qp + (size_t)(b*SM + m0 + col16) * SH + h*HD + kq;
  const bf16x8 qf0 = ld8any(qb), qf1 = ld8any(qb + 32);

  const bf16* kb = Kh + (size_t)(hb * SN) * HD + kq;
  const bf16* vb = VT + (size_t)(hb * HD) * SN;

  const int srow = tid >> 4, sj = tid & 15;  // softmax: 16 rows x 16 lanes
  float Mrun = -1.0e30f, Srun = 0.0f;
  const float span = spanv[h];
  const int dt = w * 16;
  f32x4 o = {0.f,0.f,0.f,0.f};

  for (int ch = 0; ch < 16; ++ch) {
    const int l0 = ch << 6;
    const int nb_ = m0 + l0;   // abs key base; max 496+960, +79 < 1536

    // ---- phase 1 ----
    if (w < 2) {
      f32x4 c0 = {0.f,0.f,0.f,0.f}, c1 = c0;
      const bf16* kr0 = kb + (size_t)(nb_ + w*32 + col16) * HD;
      c0 = mfma16(qf0, ld8any(kr0),      c0);
      c0 = mfma16(qf1, ld8any(kr0 + 32), c0);
      const bf16* kr1 = kr0 + 16 * HD;
      c1 = mfma16(qf0, ld8any(kr1),      c1);
      c1 = mfma16(qf1, ld8any(kr1 + 32), c1);
#pragma unroll
      for (int r = 0; r < 4; ++r) {
        cont_s[wr + r][w*32 + col16]      = c0[r];
        cont_s[wr + r][w*32 + 16 + col16] = c1[r];
      }
    } else if (w == 2) {
      f32x4 c0 = {0.f,0.f,0.f,0.f}, p0 = c0;
      const bf16* kr = kb + (size_t)(nb_ + 64 + col16) * HD;
      c0 = mfma16(qf0, ld8any(kr),      c0);
      c0 = mfma16(qf1, ld8any(kr + 32), c0);
      const bf16* pr = peT + (size_t)(l0 + col16) * HD + kq;
      p0 = mfma16(qf0, ld8any(pr),      p0);
      p0 = mfma16(qf1, ld8any(pr + 32), p0);
#pragma unroll
      for (int r = 0; r < 4; ++r) {
        cont_s[wr + r][64 + col16] = c0[r];
        pos_s[wr + r][col16]       = p0[r];
      }
    } else {
      f32x4 p1 = {0.f,0.f,0.f,0.f}, p2 = p1, p3 = p1;
      const bf16* pr1 = peT + (size_t)(l0 + 16 + col16) * HD + kq;
      p1 = mfma16(qf0, ld8any(pr1),      p1);
      p1 = mfma16(qf1, ld8any(pr1 + 32), p1);
      const bf16* pr2 = pr1 + 16 * HD;
      p2 = mfma16(qf0, ld8any(pr2),      p2);
      p2 = mfma16(qf1, ld8any(pr2 + 32), p2);
      const bf16* pr3 = pr1 + 32 * HD;
      p3 = mfma16(qf0, ld8any(pr3),      p3);
      p3 = mfma16(qf1, ld8any(pr3 + 32), p3);
#pragma unroll
      for (int r = 0; r < 4; ++r) {
        pos_s[wr + r][16 + col16] = p1[r];
        pos_s[wr + r][32 + col16] = p2[r];
        pos_s[wr + r][48 + col16] = p3[r];
      }
    }
    __syncthreads();

    // ---- phase 2: combine + online softmax (4 cols/thread) ----
    float sc[4];
    float mc = -1.0e30f;
    const float* crow = &cont_s[srow][srow + sj*4];
    const float* prow = &pos_s[srow][sj*4];
#pragma unroll
    for (int i = 0; i < 4; ++i) {
      float v = (crow[i] + prow[i]) * 0.125f;
      sc[i] = v;
      mc = fmaxf(mc, v);
    }
    mc = fmaxf(mc, __shfl_xor(mc, 1));
    mc = fmaxf(mc, __shfl_xor(mc, 2));
    mc = fmaxf(mc, __shfl_xor(mc, 4));
    mc = fmaxf(mc, __shfl_xor(mc, 8));
    const float Mnew = fmaxf(Mrun, mc);
    const float alpha = __expf(Mrun - Mnew);
    float ls = 0.0f;
    bf16* pw = &P_s[srow][srow + sj*4];
#pragma unroll
    for (int i = 0; i < 4; ++i) {
      float p = __expf(sc[i] - Mnew);
      ls += p;
      const float tpl = (float)(l0 + sj*4 + i) - 1023.0f;
      float mv = (tpl + span * 1024.0f) * 0.03125f + 1.0f;
      mv = fminf(fmaxf(mv, 0.0f), 1.0f);
      pw[i] = __float2bfloat16(p * mv);
    }
    ls += __shfl_xor(ls, 1);
    ls += __shfl_xor(ls, 2);
    ls += __shfl_xor(ls, 4);
    ls += __shfl_xor(ls, 8);
    Srun = Srun * alpha + ls;
    Mrun = Mnew;
    if (sj == 0) { alpha_s[srow] = alpha; S_s[srow] = Srun; }
    __syncthreads();

    // ---- phase 3: rescale O, PV MFMA over 96-key band ----
    float al[4];
#pragma unroll
    for (int r = 0; r < 4; ++r) al[r] = alpha_s[wr + r];
#pragma unroll
    for (int r = 0; r < 4; ++r) o[r] *= al[r];
#pragma unroll
    for (int ks = 0; ks < 3; ++ks) {
      const bf16x8 ap = ld8any(&P_s[col16][ks*32 + kq]);
      const bf16* v0 = vb + (size_t)(dt + col16) * SN + nb_ + ks*32 + kq;
      o = mfma16(ap, ld8any(v0), o);
    }
    // no barrier: next phase1 writes cont/pos only; P_s/alpha_s rewritten
    // only after the next phase1 barrier.
  }

  // ---- epilogue ----
#pragma unroll
  for (int r = 0; r < 4; ++r) {
    const float inv = 1.0f / S_s[wr + r];
    bf16* cr = ctx + (size_t)(b*SM + m0 + wr + r) * SH + h*HD + dt + col16;
    *cr = __float2bfloat16(o[r] * inv);
  }
}

// ---------------------------------------------------------------------------
// Fallback fused attention (round-6 proven): 16 rows/block, 2 waves, fused q.
// ---------------------------------------------------------------------------
#define MT 16
#define CSTR 84
#define PSTR 65
#define BSTR 104
#define QSTR 72

__global__ __launch_bounds__(128) void attn_kernel_fb(
    const float* __restrict__ query, const float* __restrict__ Wq,
    const bf16* __restrict__ Kh, const bf16* __restrict__ VT,
    const bf16* __restrict__ peT, const float* __restrict__ spanv,
    bf16* __restrict__ ctx) {
  __shared__ __align__(16) float cont_lds[MT][CSTR];
  __shared__ __align__(16) float pos_lds[MT][PSTR];
  __shared__ __align__(16) bf16  P_lds[MT][BSTR];
  __shared__ __align__(16) bf16  q_lds[MT*QSTR];
  __shared__ float alpha_lds[MT];
  __shared__ float S_lds[MT];

  const int id = blockIdx.x;
  const int h  = id & 7;
  const int s_ = id >> 3;
  const int m0 = (s_ & 31) * MT;
  const int b  = s_ >> 5;
  const int hb = b * 8 + h;
  const int tid  = threadIdx.x;
  const int lane = tid & 63;
  const int w    = tid >> 6;
  const int col16 = lane & 15, quad = lane >> 4, kq = quad << 3;
  const int wr = quad << 2;

  for (int i = tid; i < MT * BSTR; i += 128)
    (&P_lds[0][0])[i] = __float2bfloat16(0.0f);

  bf16x8 qf0, qf1;
  {
    f32x4 qa0 = {0.f,0.f,0.f,0.f}, qa1 = qa0;
    const float* xq = query + (size_t)(b*SM + m0 + col16) * SH + kq;
    const float* w0 = Wq + (size_t)(h*HD + w*32 + col16) * SH + kq;
    const float* w1 = w0 + (size_t)16 * SH;
#pragma unroll
    for (int k0 = 0; k0 < SH; k0 += 32) {
      bf16x8 xa = ld8any(xq + k0);
      qa0 = mfma16(xa, ld8any(w0 + k0), qa0);
      qa1 = mfma16(xa, ld8any(w1 + k0), qa1);
    }
#pragma unroll
    for (int r = 0; r < 4; ++r) {
      q_lds[(wr + r)*QSTR + w*32 + col16]      = __float2bfloat16(qa0[r]);
      q_lds[(wr + r)*QSTR + w*32 + 16 + col16] = __float2bfloat16(qa1[r]);
    }
    __syncthreads();
    qf0 = ld8any(&q_lds[col16*QSTR + kq]);
    qf1 = ld8any(&q_lds[col16*QSTR + kq + 32]);
  }

  const bf16* kb = Kh + (size_t)(hb * SN) * HD + kq;
  const bf16* vb = VT + (size_t)(hb * HD) * SN;

  const int srow = tid >> 3, sj = tid & 7;
  float Mrun = -1.0e30f, Srun = 0.0f;
  const float span = spanv[h];
  const int dt0 = w * 16, dt1 = (w + 2) * 16;
  f32x4 o0 = {0.f,0.f,0.f,0.f}, o1 = o0;

  for (int ch = 0; ch < 16; ++ch) {
    const int l0 = ch << 6;
    const int nb_ = m0 + l0;

    f32x4 ca0 = {0.f,0.f,0.f,0.f}, ca1 = ca0, ca2 = ca0, pa0 = ca0, pa1 = ca0;
    {
      const bf16* kr0 = kb + (size_t)(nb_ + w*16 + col16) * HD;
      ca0 = mfma16(qf0, ld8any(kr0),           ca0);
      ca0 = mfma16(qf1, ld8any(kr0 + 32),      ca0);
      const bf16* kr1 = kr0 + 32 * HD;
      ca1 = mfma16(qf0, ld8any(kr1),           ca1);
      ca1 = mfma16(qf1, ld8any(kr1 + 32),      ca1);
      if (w == 0) {
        const bf16* kr2 = kr0 + 64 * HD;
        ca2 = mfma16(qf0, ld8any(kr2),         ca2);
        ca2 = mfma16(qf1, ld8any(kr2 + 32),    ca2);
      }
      const bf16* pr0 = peT + (size_t)(l0 + w*16 + col16) * HD + kq;
      pa0 = mfma16(qf0, ld8any(pr0),           pa0);
      pa0 = mfma16(qf1, ld8any(pr0 + 32),      pa0);
      const bf16* pr1 = pr0 + 32 * HD;
      pa1 = mfma16(qf0, ld8any(pr1),           pa1);
      pa1 = mfma16(qf1, ld8any(pr1 + 32),      pa1);
    }
#pragma unroll
    for (int r = 0; r < 4; ++r) {
      cont_lds[wr + r][w*16 + col16]      = ca0[r];
      cont_lds[wr + r][w*16 + 32 + col16] = ca1[r];
      if (w == 0) cont_lds[wr + r][64 + col16] = ca2[r];
      pos_lds[wr + r][w*16 + col16]       = pa0[r];
      pos_lds[wr + r][w*16 + 32 + col16]  = pa1[r];
    }
    __syncthreads();

    float sc[8];
    float mc = -1.0e30f;
    const float* crow = &cont_lds[srow][srow + sj*8];
    const float* prow = &pos_lds[srow][sj*8];
#pragma unroll
    for (int i = 0; i < 8; ++i) {
      float v = (crow[i] + prow[i]) * 0.125f;
      sc[i] = v;
      mc = fmaxf(mc, v);
    }
    mc = fmaxf(mc, __shfl_xor(mc, 1));
    mc = fmaxf(mc, __shfl_xor(mc, 2));
    mc = fmaxf(mc, __shfl_xor(mc, 4));
    const float Mnew = fmaxf(Mrun, mc);
    const float alpha = __expf(Mrun - Mnew);
    float ls = 0.0f;
    bf16* pwrow = &P_lds[srow][srow + sj*8];
#pragma unroll
    for (int i = 0; i < 8; ++i) {
      float p = __expf(sc[i] - Mnew);
      ls += p;
      const float tpl = (float)(l0 + sj*8 + i) - 1023.0f;
      float mv = (tpl + span * 1024.0f) * 0.03125f + 1.0f;
      mv = fminf(fmaxf(mv, 0.0f), 1.0f);
      pwrow[i] = __float2bfloat16(p * mv);
    }
    ls += __shfl_xor(ls, 1);
    ls += __shfl_xor(ls, 2);
    ls += __shfl_xor(ls, 4);
    Srun = Srun * alpha + ls;
    Mrun = Mnew;
    if (sj == 0) { alpha_lds[srow] = alpha; S_lds[srow] = Srun; }
    __syncthreads();

    float al[4];
#pragma unroll
    for (int r = 0; r < 4; ++r) al[r] = alpha_lds[wr + r];
#pragma unroll
    for (int r = 0; r < 4; ++r) { o0[r] *= al[r]; o1[r] *= al[r]; }
#pragma unroll
    for (int ks = 0; ks < 3; ++ks) {
      const bf16x8 ap = ld8any(&P_lds[col16][ks*32 + kq]);
      const bf16* v0 = vb + (size_t)(dt0 + col16) * SN + nb_ + ks*32 + kq;
      const bf16* v1 = vb + (size_t)(dt1 + col16) * SN + nb_ + ks*32 + kq;
      o0 = mfma16(ap, ld8any(v0), o0);
      o1 = mfma16(ap, ld8any(v1), o1);
    }
  }

  bf16* cr = ctx + (size_t)(b*SM + m0 + wr) * SH + h*HD + col16;
#pragma unroll
  for (int r = 0; r < 4; ++r) {
    const float inv = 1.0f / S_lds[wr + r];
    cr[(size_t)r * SH + dt0] = __float2bfloat16(o0[r] * inv);
    cr[(size_t)r * SH + dt1] = __float2bfloat16(o1[r] * inv);
  }
}

// ---------------------------------------------------------------------------
extern "C" void kernel_launch(void* const* d_in, const int* in_sizes, int n_in,
                              void* d_out, int out_size, void* d_ws, size_t ws_size,
                              hipStream_t stream) {
  const float* query  = (const float*)d_in[0];
  const float* key    = (const float*)d_in[1];
  const float* value  = (const float*)d_in[2];
  const float* key_pe = (const float*)d_in[3];
  const float* Wq     = (const float*)d_in[4];
  const float* Wk     = (const float*)d_in[5];
  const float* Wv     = (const float*)d_in[6];
  const float* Wo     = (const float*)d_in[7];
  const float* spanv  = (const float*)d_in[8];
  float* out = (float*)d_out;

  bf16* ws = (bf16*)d_ws;
  if (ws_size >= (size_t)48365568) {
    // Path C: bf16-converted pipeline, 48.4 MB ws.
    bf16* stg    = ws;                    // 6291456 el, reused key->value
    bf16* k_head = stg    + 6291456;
    bf16* vT     = k_head + 6291456;
    bf16* qp     = vT     + 6291456;
    bf16* ctx    = qp     + 2097152;
    bf16* peT    = ctx    + 2097152;
    bf16* Wb     = peT    + 65536;
    bf16* Wq_b = Wb, *Wk_b = Wb + 262144, *Wv_b = Wb + 524288, *Wo_b = Wb + 786432;

    conv_w4<<<dim3(128, 4), 256, 0, stream>>>(Wq, Wk, Wv, Wo, Wb);
    transpose_pe<<<256, 256, 0, stream>>>(key_pe, peT);

    conv_bf16<<<3072, 256, 0, stream>>>(key, stg);
    gemmbn64<1, bf16, bf16, bf16><<<768, 256, 0, stream>>>(stg, Wk_b, k_head);
    conv_bf16<<<3072, 256, 0, stream>>>(value, stg);
    gemmbn64<2, bf16, bf16, bf16><<<768, 256, 0, stream>>>(stg, Wv_b, vT);
    gemmbn64<0, float, bf16, bf16><<<256, 256, 0, stream>>>(query, Wq_b, qp);

    attn4<<<2048, 256, 0, stream>>>(qp, k_head, vT, peT, spanv, ctx);
    gemmbn64<0, bf16, bf16, float><<<256, 256, 0, stream>>>(ctx, Wo_b, out);
  } else {
    // Path B (fallback): fused-q attention, f32 GEMM reads, 29.5 MB ws.
    bf16* k_head = ws;
    bf16* vT     = k_head + 6291456;
    bf16* ctx    = vT     + 6291456;
    bf16* peT    = ctx    + 2097152;
    gemmbn64<1, float, float, bf16><<<768, 256, 0, stream>>>(key,   Wk, k_head);
    gemmbn64<2, float, float, bf16><<<768, 256, 0, stream>>>(value, Wv, vT);
    transpose_pe<<<256, 256, 0, stream>>>(key_pe, peT);
    attn_kernel_fb<<<2048, 128, 0, stream>>>(query, Wq, k_head, vT,
                                             peT, spanv, ctx);
    gemmbn64<0, bf16, float, float><<<256, 256, 0, stream>>>(ctx, Wo, out);
  }
}